// Round 1
// baseline (225.742 us; speedup 1.0000x reference)
//
#include <hip/hip_runtime.h>

// Bilateral slice: grid (N=4, C=12, GD=8, GH=16, GW=16) fp32,
// guide (N,1,1024,1024) fp32 -> out (N, C, 1024, 1024) fp32.
//
// One block per image row. y-lerp of the grid is uniform per row ->
// precompute r in LDS once per block, then each pixel does a 4-tap (x,z)
// bilinear per channel.
//
// LDS layout r[x][z][c], dword index = x*97 + z*12 + c:
//  - bank = (x + 12z + c) % 32 is injective over the wave's (x&3, z) set
//    -> zero bank conflicts on tap reads (duplicates broadcast).
//  - 4 taps per (c,pixel) at dword offsets {c, c+12, c+97, c+109} from one
//    base -> two ds_read2_b32 with immediate offsets, no per-channel addr math.

#define NN 4
#define CC 12
#define GD_ 8
#define GH_ 16
#define GW_ 16
#define HH 1024
#define WW 1024

#define ZSTR 12   // z stride in dwords (= CC)
#define XSTR 97   // x stride in dwords (odd, == 1 mod 32)

__global__ __launch_bounds__(256) void slice_kernel(
    const float* __restrict__ grid,   // (N, C, GD, GH, GW)
    const float* __restrict__ guide,  // (N, 1, H, W)
    float* __restrict__ out)          // (N, C, H, W)
{
    __shared__ float r[GW_ * XSTR + 4];   // 1556 dwords = 6224 B

    const int row = blockIdx.x;        // 0 .. N*H-1
    const int n   = row >> 10;
    const int y   = row & (HH - 1);
    const int tid = threadIdx.x;

    // ---- y weights (uniform across the row) ----
    float ys = ((float)y + 0.5f) * (1.0f / 64.0f);   // * GH / H
    float fy = floorf(ys - 0.5f);
    int   by = (int)fy;
    by = by < 0 ? 0 : (by > GH_ - 2 ? GH_ - 2 : by);
    float ty = (ys - 0.5f) - (float)by;              // == (ys-.5-fy)+(fy-by)
    ty = ty < 0.0f ? 0.0f : (ty > 1.0f ? 1.0f : ty);
    const float wy0 = 1.0f - ty, wy1 = ty;

    // ---- stage y-lerped grid into LDS (r[x][z][c]) ----
    const float* gbase = grid + (size_t)n * (CC * GD_ * GH_ * GW_);
    for (int idx = tid; idx < CC * GD_ * GW_; idx += 256) {
        int gx = idx & 15;
        int z  = (idx >> 4) & 7;
        int c  = idx >> 7;
        const float* gp = gbase + ((c * GD_ + z) * GH_) * GW_ + gx;
        float g0 = gp[by * GW_];
        float g1 = gp[(by + 1) * GW_];
        r[gx * XSTR + z * ZSTR + c] = wy0 * g0 + wy1 * g1;
    }
    __syncthreads();

    // ---- per-pixel setup: 4 consecutive pixels per thread ----
    const float4 g4 = ((const float4*)guide)[((size_t)n * HH + y) * (WW / 4) + tid];
    float gz[4] = {g4.x, g4.y, g4.z, g4.w};

    // bx is uniform across the thread's 4 pixels: fx = floor((x-31.5)/64)
    // changes only at x = 32 + 64k, which never falls inside an aligned
    // group of 4. tx_j = clamp(tx0 + j/64) is bit-exact vs per-pixel compute.
    const int x0 = tid * 4;
    float xs  = ((float)x0 + 0.5f) * (1.0f / 64.0f);  // * GW / W
    float fx  = floorf(xs - 0.5f);
    int   bx  = (int)fx;
    bx = bx < 0 ? 0 : (bx > GW_ - 2 ? GW_ - 2 : bx);
    const float txb = (xs - 0.5f) - (float)bx;        // clamped per-j below

    const float* rb = r + bx * XSTR;
    const float* rj[4];
    float w00[4], w01[4], w10[4], w11[4];
#pragma unroll
    for (int j = 0; j < 4; ++j) {
        float tx = txb + (float)j * (1.0f / 64.0f);
        tx = tx < 0.0f ? 0.0f : (tx > 1.0f ? 1.0f : tx);

        float zs = gz[j] * 8.0f;                      // * GD
        float fz = floorf(zs - 0.5f);
        int   bz = (int)fz;
        bz = bz < 0 ? 0 : (bz > GD_ - 2 ? GD_ - 2 : bz);
        float tz = (zs - 0.5f) - (float)bz;
        tz = tz < 0.0f ? 0.0f : (tz > 1.0f ? 1.0f : tz);

        rj[j] = rb + bz * ZSTR;
        float tx0 = 1.0f - tx, tz0 = 1.0f - tz;
        w00[j] = tz0 * tx0;  w01[j] = tz0 * tx;       // (bx,bz)   (bx+1,bz)
        w10[j] = tz  * tx0;  w11[j] = tz  * tx;       // (bx,bz+1) (bx+1,bz+1)
    }

    // ---- channel loop: 4 taps = 2x ds_read2_b32 per pixel, float4 store ----
    float4* out4 = (float4*)out + ((size_t)(n * CC) * HH + y) * (WW / 4) + tid;
#pragma unroll
    for (int c = 0; c < CC; ++c) {
        float acc[4];
#pragma unroll
        for (int j = 0; j < 4; ++j) {
            const float* p = rj[j];
            float t00 = p[c];                  // (bx,   bz)
            float t10 = p[c + ZSTR];           // (bx,   bz+1)
            float t01 = p[c + XSTR];           // (bx+1, bz)
            float t11 = p[c + XSTR + ZSTR];    // (bx+1, bz+1)
            acc[j] = w00[j] * t00 + w10[j] * t10 + w01[j] * t01 + w11[j] * t11;
        }
        out4[(size_t)c * (HH * WW / 4)] = make_float4(acc[0], acc[1], acc[2], acc[3]);
    }
}

extern "C" void kernel_launch(void* const* d_in, const int* in_sizes, int n_in,
                              void* d_out, int out_size, void* d_ws, size_t ws_size,
                              hipStream_t stream) {
    const float* grid  = (const float*)d_in[0];
    const float* guide = (const float*)d_in[1];
    float* out = (float*)d_out;
    dim3 gridDim(NN * HH);
    dim3 blockDim(256);
    hipLaunchKernelGGL(slice_kernel, gridDim, blockDim, 0, stream, grid, guide, out);
}

// Round 2
// 210.462 us; speedup vs baseline: 1.0726x; 1.0726x over previous
//
#include <hip/hip_runtime.h>

// Bilateral slice: grid (N=4, C=12, GD=8, GH=16, GW=16) fp32,
// guide (N,1,1024,1024) fp32 -> out (N, C, 1024, 1024) fp32.
//
// One block per image row. y-lerp of the grid is uniform per row ->
// precompute r in LDS once per block, then each pixel does a 4-tap (x,z)
// bilinear per channel.
//
// LDS layout r[x][z][c], dword index = x*100 + z*12 + c:
//  - channels contiguous -> the 4 taps for a 4-channel group are 4x
//    ds_read_b128 at immediate byte offsets {0,48,400,448}+16*g from ONE
//    per-pixel base: 12 LDS instr / pixel (the 16B/lane floor), zero
//    address VALU in the channel loop.
//  - XSTR=100 = 4 (mod 32) and multiple of 4: all float4 reads 16B-aligned;
//    lane bank groups are aligned 4-bank slots; collisions are >=2-way
//    broadcast/free in the common case.

#define NN 4
#define CC 12
#define GD_ 8
#define GH_ 16
#define GW_ 16
#define HH 1024
#define WW 1024

#define ZSTR 12    // z stride in dwords (= CC), multiple of 4
#define XSTR 100   // x stride in dwords, multiple of 4, == 4 mod 32

__global__ __launch_bounds__(256, 4) void slice_kernel(
    const float* __restrict__ grid,   // (N, C, GD, GH, GW)
    const float* __restrict__ guide,  // (N, 1, H, W)
    float* __restrict__ out)          // (N, C, H, W)
{
    __shared__ float r[GW_ * XSTR];   // 1600 dwords = 6400 B

    const int row = blockIdx.x;        // 0 .. N*H-1
    const int n   = row >> 10;
    const int y   = row & (HH - 1);
    const int tid = threadIdx.x;

    // ---- guide load first: HBM latency hides under staging ----
    const float4 g4 = ((const float4*)guide)[((size_t)n * HH + y) * (WW / 4) + tid];

    // ---- y weights (uniform across the row) ----
    float ys = ((float)y + 0.5f) * (1.0f / 64.0f);   // * GH / H
    float fy = floorf(ys - 0.5f);
    int   by = (int)fy;
    by = by < 0 ? 0 : (by > GH_ - 2 ? GH_ - 2 : by);
    float ty = (ys - 0.5f) - (float)by;
    ty = ty < 0.0f ? 0.0f : (ty > 1.0f ? 1.0f : ty);
    const float wy0 = 1.0f - ty, wy1 = ty;

    // ---- stage y-lerped grid into LDS r[x][z][c], fully unrolled ----
    const float* gbase = grid + (size_t)n * (CC * GD_ * GH_ * GW_) + by * GW_;
#pragma unroll
    for (int it = 0; it < 6; ++it) {
        int idx = tid + it * 256;      // 0..1535
        int gx = idx & 15;
        int z  = (idx >> 4) & 7;
        int c  = idx >> 7;
        const float* gp = gbase + ((c * GD_ + z) * GH_) * GW_ + gx;
        float g0 = gp[0];
        float g1 = gp[GW_];
        r[gx * XSTR + z * ZSTR + c] = wy0 * g0 + wy1 * g1;
    }

    // ---- per-pixel setup BEFORE the barrier (no LDS dependency) ----
    // bx is uniform across the thread's 4 pixels: fx = floor((x-31.5)/64)
    // changes only at x = 32 + 64k, never inside an aligned group of 4.
    const int x0 = tid * 4;
    float xs  = ((float)x0 + 0.5f) * (1.0f / 64.0f);  // * GW / W
    float fx  = floorf(xs - 0.5f);
    int   bx  = (int)fx;
    bx = bx < 0 ? 0 : (bx > GW_ - 2 ? GW_ - 2 : bx);
    const float txb = (xs - 0.5f) - (float)bx;

    float gz[4] = {g4.x, g4.y, g4.z, g4.w};
    int   aoff[4];                       // per-pixel LDS dword base
    float w00[4], w01[4], w10[4], w11[4];
#pragma unroll
    for (int j = 0; j < 4; ++j) {
        float tx = txb + (float)j * (1.0f / 64.0f);
        tx = tx < 0.0f ? 0.0f : (tx > 1.0f ? 1.0f : tx);

        float zs = gz[j] * 8.0f;                      // * GD
        float fz = floorf(zs - 0.5f);
        int   bz = (int)fz;
        bz = bz < 0 ? 0 : (bz > GD_ - 2 ? GD_ - 2 : bz);
        float tz = (zs - 0.5f) - (float)bz;
        tz = tz < 0.0f ? 0.0f : (tz > 1.0f ? 1.0f : tz);

        aoff[j] = bx * XSTR + bz * ZSTR;
        float tx0 = 1.0f - tx, tz0 = 1.0f - tz;
        w00[j] = tz0 * tx0;  w01[j] = tz0 * tx;       // (bx,bz)   (bx+1,bz)
        w10[j] = tz  * tx0;  w11[j] = tz  * tx;       // (bx,bz+1) (bx+1,bz+1)
    }

    __syncthreads();

    // ---- channel loop: 3 groups of 4 channels; per (group, pixel) the 4
    //      taps are 4x float4 = 4x ds_read_b128, immediate offsets only ----
    float4* out4 = (float4*)out + ((size_t)(n * CC) * HH + y) * (WW / 4) + tid;
#pragma unroll
    for (int g = 0; g < 3; ++g) {
        float acc[4][4];                 // [cc][j]
#pragma unroll
        for (int j = 0; j < 4; ++j) {
            const float* p = r + aoff[j] + 4 * g;
            const float4 t00 = *(const float4*)(p);                 // (bx,  bz)
            const float4 t10 = *(const float4*)(p + ZSTR);          // (bx,  bz+1)
            const float4 t01 = *(const float4*)(p + XSTR);          // (bx+1,bz)
            const float4 t11 = *(const float4*)(p + XSTR + ZSTR);   // (bx+1,bz+1)
            acc[0][j] = w00[j]*t00.x + w10[j]*t10.x + w01[j]*t01.x + w11[j]*t11.x;
            acc[1][j] = w00[j]*t00.y + w10[j]*t10.y + w01[j]*t01.y + w11[j]*t11.y;
            acc[2][j] = w00[j]*t00.z + w10[j]*t10.z + w01[j]*t01.z + w11[j]*t11.z;
            acc[3][j] = w00[j]*t00.w + w10[j]*t10.w + w01[j]*t01.w + w11[j]*t11.w;
        }
#pragma unroll
        for (int cc = 0; cc < 4; ++cc) {
            int c = 4 * g + cc;
            out4[(size_t)c * (HH * WW / 4)] =
                make_float4(acc[cc][0], acc[cc][1], acc[cc][2], acc[cc][3]);
        }
    }
}

extern "C" void kernel_launch(void* const* d_in, const int* in_sizes, int n_in,
                              void* d_out, int out_size, void* d_ws, size_t ws_size,
                              hipStream_t stream) {
    const float* grid  = (const float*)d_in[0];
    const float* guide = (const float*)d_in[1];
    float* out = (float*)d_out;
    dim3 gridDim(NN * HH);
    dim3 blockDim(256);
    hipLaunchKernelGGL(slice_kernel, gridDim, blockDim, 0, stream, grid, guide, out);
}

// Round 4
// 207.158 us; speedup vs baseline: 1.0897x; 1.0159x over previous
//
#include <hip/hip_runtime.h>

// Bilateral slice: grid (N=4, C=12, GD=8, GH=16, GW=16) fp32,
// guide (N,1,1024,1024) fp32 -> out (N, C, 1024, 1024) fp32.
//
// One block per ROW PAIR (y, y+1). Row pairs always share the y-cell `by`
// (fy increments between y=64k+31 and 64k+32, i.e. between even-aligned
// pairs), so one set of grid loads feeds both rows' y-lerped LDS tables:
// staging loads and barriers are halved vs one-row blocks, and each block
// writes 8 KiB contiguous per channel plane.
//
// LDS layout r[row][x][z][c], dword index = x*100 + z*12 + c:
//  - channels contiguous -> the 4 taps for a 4-channel group are 4x
//    ds_read_b128 at immediate byte offsets {0,48,400,448}+16*g from ONE
//    per-pixel base: 12 LDS instr / pixel (the 16B/lane floor), zero
//    address VALU in the channel loop.
//  - XSTR=100 = 4 (mod 32), multiple of 4: 16B-aligned float4 reads,
//    bank collisions <=2-way (free) on both staging writes and tap reads.

#define NN 4
#define CC 12
#define GD_ 8
#define GH_ 16
#define GW_ 16
#define HH 1024
#define WW 1024

#define ZSTR 12    // z stride in dwords (= CC)
#define XSTR 100   // x stride in dwords

__global__ __launch_bounds__(512) void slice_kernel(
    const float* __restrict__ grid,   // (N, C, GD, GH, GW)
    const float* __restrict__ guide,  // (N, 1, H, W)
    float* __restrict__ out)          // (N, C, H, W)
{
    __shared__ float r[2][GW_ * XSTR];   // 2 x 1600 dwords = 12.8 KB

    const int bid  = blockIdx.x;         // 0 .. N*H/2-1
    const int n    = bid >> 9;
    const int y0   = (bid & 511) << 1;   // even row
    const int tid  = threadIdx.x;        // 0..511
    const int rsel = tid >> 8;           // 0: row y0, 1: row y0+1 (wave-uniform)
    const int lane = tid & 255;
    const int y    = y0 + rsel;

    // ---- guide load first: HBM latency hides under staging ----
    const float4 g4 = ((const float4*)guide)[((size_t)n * HH + y) * (WW / 4) + lane];

    // ---- y weights for both rows (shared by) ----
    float ys0 = ((float)y0 + 0.5f) * (1.0f / 64.0f);   // * GH / H
    float fy  = floorf(ys0 - 0.5f);
    int   by  = (int)fy;
    by = by < 0 ? 0 : (by > GH_ - 2 ? GH_ - 2 : by);
    float ty0 = (ys0 - 0.5f) - (float)by;
    ty0 = ty0 < 0.0f ? 0.0f : (ty0 > 1.0f ? 1.0f : ty0);
    float ty1 = (ys0 + (1.0f / 64.0f) - 0.5f) - (float)by;
    ty1 = ty1 < 0.0f ? 0.0f : (ty1 > 1.0f ? 1.0f : ty1);

    // ---- stage y-lerped grid for BOTH rows, fully unrolled ----
    const float* gbase = grid + (size_t)n * (CC * GD_ * GH_ * GW_) + by * GW_;
#pragma unroll
    for (int it = 0; it < 3; ++it) {
        int idx = tid + it * 512;      // 0..1535
        int gx = idx & 15;
        int z  = (idx >> 4) & 7;
        int c  = idx >> 7;
        const float* gp = gbase + ((c * GD_ + z) * GH_) * GW_ + gx;
        float g0 = gp[0];
        float g1 = gp[GW_];
        int a = gx * XSTR + z * ZSTR + c;
        r[0][a] = (1.0f - ty0) * g0 + ty0 * g1;
        r[1][a] = (1.0f - ty1) * g0 + ty1 * g1;
    }

    // ---- per-pixel setup BEFORE the barrier (no LDS dependency) ----
    // bx uniform across a thread's 4 aligned pixels (fx changes at x=64k+32).
    const int x0 = lane * 4;
    float xs  = ((float)x0 + 0.5f) * (1.0f / 64.0f);  // * GW / W
    float fx  = floorf(xs - 0.5f);
    int   bx  = (int)fx;
    bx = bx < 0 ? 0 : (bx > GW_ - 2 ? GW_ - 2 : bx);
    const float txb = (xs - 0.5f) - (float)bx;

    float gz[4] = {g4.x, g4.y, g4.z, g4.w};
    int   aoff[4];
    float w00[4], w01[4], w10[4], w11[4];
#pragma unroll
    for (int j = 0; j < 4; ++j) {
        float tx = txb + (float)j * (1.0f / 64.0f);
        tx = tx < 0.0f ? 0.0f : (tx > 1.0f ? 1.0f : tx);

        float zs = gz[j] * 8.0f;                      // * GD
        float fz = floorf(zs - 0.5f);
        int   bz = (int)fz;
        bz = bz < 0 ? 0 : (bz > GD_ - 2 ? GD_ - 2 : bz);
        float tz = (zs - 0.5f) - (float)bz;
        tz = tz < 0.0f ? 0.0f : (tz > 1.0f ? 1.0f : tz);

        aoff[j] = bx * XSTR + bz * ZSTR;
        float tx0 = 1.0f - tx, tz0 = 1.0f - tz;
        w00[j] = tz0 * tx0;  w01[j] = tz0 * tx;       // (bx,bz)   (bx+1,bz)
        w10[j] = tz  * tx0;  w11[j] = tz  * tx;       // (bx,bz+1) (bx+1,bz+1)
    }

    __syncthreads();

    // ---- channel loop: 3 groups of 4 channels; per (group, pixel) the 4
    //      taps are 4x ds_read_b128, immediate offsets only ----
    const float* rr = r[rsel];
    float4* out4 = (float4*)out + ((size_t)(n * CC) * HH + y) * (WW / 4) + lane;
#pragma unroll
    for (int g = 0; g < 3; ++g) {
        float acc[4][4];                 // [cc][j]
#pragma unroll
        for (int j = 0; j < 4; ++j) {
            const float* p = rr + aoff[j] + 4 * g;
            const float4 t00 = *(const float4*)(p);                 // (bx,  bz)
            const float4 t10 = *(const float4*)(p + ZSTR);          // (bx,  bz+1)
            const float4 t01 = *(const float4*)(p + XSTR);          // (bx+1,bz)
            const float4 t11 = *(const float4*)(p + XSTR + ZSTR);   // (bx+1,bz+1)
            acc[0][j] = w00[j]*t00.x + w10[j]*t10.x + w01[j]*t01.x + w11[j]*t11.x;
            acc[1][j] = w00[j]*t00.y + w10[j]*t10.y + w01[j]*t01.y + w11[j]*t11.y;
            acc[2][j] = w00[j]*t00.z + w10[j]*t10.z + w01[j]*t01.z + w11[j]*t11.z;
            acc[3][j] = w00[j]*t00.w + w10[j]*t10.w + w01[j]*t01.w + w11[j]*t11.w;
        }
#pragma unroll
        for (int cc = 0; cc < 4; ++cc) {
            int c = 4 * g + cc;
            out4[(size_t)c * (HH * WW / 4)] =
                make_float4(acc[cc][0], acc[cc][1], acc[cc][2], acc[cc][3]);
        }
    }
}

extern "C" void kernel_launch(void* const* d_in, const int* in_sizes, int n_in,
                              void* d_out, int out_size, void* d_ws, size_t ws_size,
                              hipStream_t stream) {
    const float* grid  = (const float*)d_in[0];
    const float* guide = (const float*)d_in[1];
    float* out = (float*)d_out;
    dim3 gridDim(NN * HH / 2);
    dim3 blockDim(512);
    hipLaunchKernelGGL(slice_kernel, gridDim, blockDim, 0, stream, grid, guide, out);
}